// Round 7
// baseline (442.025 us; speedup 1.0000x reference)
//
#include <hip/hip_runtime.h>

#define NFEAT 128
#define NHID 64
#define NCLASS 40

#define BSH 8                    // CSR-build bin = 256 nodes
#define MAXBIN 512               // supports N <= 131072
#define CH 2048                  // edges per chunk in pass A (784 blocks -> >2 per CU)

// ---------------- bf16 helpers (storage-only precision; compute is fp32) ----------------

__device__ __forceinline__ float bfu(unsigned short u) {
    return __uint_as_float((unsigned)u << 16);
}
__device__ __forceinline__ unsigned short fbf(float f) {
    unsigned u = __float_as_uint(f);
    u += 0x7fffu + ((u >> 16) & 1u);        // round-to-nearest-even
    return (unsigned short)(u >> 16);
}
// unpack uint2 (4 packed bf16) -> float4
__device__ __forceinline__ float4 up4(uint2 u) {
    return make_float4(__uint_as_float(u.x << 16), __uint_as_float(u.x & 0xffff0000u),
                       __uint_as_float(u.y << 16), __uint_as_float(u.y & 0xffff0000u));
}

// ======================= CSR build, hierarchical =======================

__launch_bounds__(256)
__global__ void binA1(const int* __restrict__ dst, int* __restrict__ gcount, int E, int nbin) {
    __shared__ int h[MAXBIN];
    const int t = threadIdx.x;
    for (int i = t; i < nbin; i += 256) h[i] = 0;
    __syncthreads();
    const int e0 = blockIdx.x * CH;
    const int e1 = min(e0 + CH, E);
    for (int i = e0 + t; i < e1; i += 256) atomicAdd(&h[dst[i] >> BSH], 1);
    __syncthreads();
    for (int i = t; i < nbin; i += 256) { int c = h[i]; if (c) atomicAdd(&gcount[i], c); }
}

__launch_bounds__(512)
__global__ void binscan(const int* __restrict__ gcount, int* __restrict__ gbase,
                        int* __restrict__ gcur, int* __restrict__ row_ptr,
                        int nbin, int N, int E) {
    __shared__ int sd[512];
    const int t = threadIdx.x;
    int v = (t < nbin) ? gcount[t] : 0;
    sd[t] = v;
    __syncthreads();
    for (int off = 1; off < 512; off <<= 1) {
        int tmp = (t >= off) ? sd[t - off] : 0;
        __syncthreads();
        sd[t] += tmp;
        __syncthreads();
    }
    int excl = sd[t] - v;
    if (t < nbin) { gbase[t] = excl; gcur[t] = excl; }
    if (t == 0) { gbase[nbin] = E; row_ptr[N] = E; }
}

// A2: reserve a contiguous run per bin, scatter packed (local_dst<<24 | src).
__launch_bounds__(256)
__global__ void binA2(const int* __restrict__ src, const int* __restrict__ dst,
                      int* __restrict__ gcur, unsigned* __restrict__ ebuf, int E, int nbin) {
    __shared__ int h[MAXBIN];
    __shared__ int base[MAXBIN];
    const int t = threadIdx.x;
    for (int i = t; i < nbin; i += 256) h[i] = 0;
    __syncthreads();
    const int e0 = blockIdx.x * CH;
    const int e1 = min(e0 + CH, E);
    for (int i = e0 + t; i < e1; i += 256) atomicAdd(&h[dst[i] >> BSH], 1);
    __syncthreads();
    for (int i = t; i < nbin; i += 256) {
        int c = h[i];
        if (c) base[i] = atomicAdd(&gcur[i], c);
        h[i] = 0;
    }
    __syncthreads();
    for (int i = e0 + t; i < e1; i += 256) {
        int d = dst[i];
        int b = d >> BSH;
        int pos = base[b] + atomicAdd(&h[b], 1);
        ebuf[pos] = ((unsigned)(d & ((1 << BSH) - 1)) << 24) | (unsigned)src[i];
    }
}

// B: one wg per 256-node bin: LDS count -> scan -> row_ptr + dinv + csr scatter.
__launch_bounds__(256)
__global__ void binB(const unsigned* __restrict__ ebuf, const int* __restrict__ gbase,
                     int* __restrict__ row_ptr, float* __restrict__ dinv,
                     int* __restrict__ csr_src, int N) {
    __shared__ int cnt[256];
    __shared__ int sd[256];
    __shared__ int cur[256];
    const int b = blockIdx.x;
    const int n0 = b << BSH;
    const int t = threadIdx.x;
    const int b0 = gbase[b], b1 = gbase[b + 1];
    cnt[t] = 0;
    __syncthreads();
    for (int i = b0 + t; i < b1; i += 256) atomicAdd(&cnt[ebuf[i] >> 24], 1);
    __syncthreads();
    int v = cnt[t];
    sd[t] = v;
    __syncthreads();
    for (int off = 1; off < 256; off <<= 1) {
        int tmp = (t >= off) ? sd[t - off] : 0;
        __syncthreads();
        sd[t] += tmp;
        __syncthreads();
    }
    int excl = sd[t] - v;
    int n = n0 + t;
    if (n < N) {
        row_ptr[n] = b0 + excl;
        dinv[n] = rsqrtf((float)v + 1.0f);      // +1 self loop
    }
    cur[t] = b0 + excl;
    __syncthreads();
    for (int i = b0 + t; i < b1; i += 256) {
        unsigned p = ebuf[i];
        int pos = atomicAdd(&cur[p >> 24], 1);
        csr_src[pos] = (int)(p & 0xffffffu);
    }
}

// ======================= dense linear =======================
// out[n,:] = bf16( dinv[n] * (f(in[n,:]) @ W) ), f = relu(x + bias_prev) if RELU_BIAS.
// IN_BF16 inputs are 2-plane (32 features per plane); OUT2 selects 2-plane output.

template<int K, int F, bool RELU_BIAS, bool IN_BF16, bool OUT2>
__launch_bounds__(256)
__global__ void lin_kernel(const void* __restrict__ in_, const float* __restrict__ W,
                           const float* __restrict__ bias, const float* __restrict__ dinv,
                           unsigned short* __restrict__ out, int N) {
    constexpr int FT = F / 4;
    constexpr int TG = 256 / FT;
    constexpr int NPT = 4;
    constexpr int NODES = TG * NPT;
    constexpr int KP = K + 4;

    __shared__ alignas(16) float Ws[K * F];
    __shared__ alignas(16) float xs[NODES * KP];

    const int tid = threadIdx.x;
    const int n0 = blockIdx.x * NODES;
    const size_t PS = (size_t)N * 32;        // plane stride (bf16 elements)

    for (int q = tid; q < K * F / 4; q += 256)
        ((float4*)Ws)[q] = ((const float4*)W)[q];

    if constexpr (IN_BF16) {
        const unsigned short* in = (const unsigned short*)in_;
        for (int q = tid; q < NODES * (K / 8); q += 256) {
            int ni = q / (K / 8);
            int c = q - ni * (K / 8);        // 8-feature chunk, 0..K/8-1
            int n = n0 + ni;
            float v[8];
            if (n < N) {
                int p = c >> 2;              // plane (K=64: c 0..7 -> p 0..1)
                int col = (c & 3) * 8;
                uint4 raw = *(const uint4*)(in + p * PS + (size_t)n * 32 + col);
                unsigned rr[4] = {raw.x, raw.y, raw.z, raw.w};
                #pragma unroll
                for (int j = 0; j < 4; ++j) {
                    v[2 * j]     = __uint_as_float(rr[j] << 16);
                    v[2 * j + 1] = __uint_as_float(rr[j] & 0xffff0000u);
                }
            } else {
                #pragma unroll
                for (int j = 0; j < 8; ++j) v[j] = 0.f;
            }
            if constexpr (RELU_BIAS) {
                #pragma unroll
                for (int j = 0; j < 8; ++j) v[j] = fmaxf(v[j] + bias[c * 8 + j], 0.f);
            }
            *(float4*)&xs[ni * KP + c * 8]     = make_float4(v[0], v[1], v[2], v[3]);
            *(float4*)&xs[ni * KP + c * 8 + 4] = make_float4(v[4], v[5], v[6], v[7]);
        }
    } else {
        const float* in = (const float*)in_;
        for (int q = tid; q < NODES * (K / 4); q += 256) {
            int ni = q / (K / 4);
            int kq = q - ni * (K / 4);
            int n = n0 + ni;
            float4 v = make_float4(0.f, 0.f, 0.f, 0.f);
            if (n < N) v = ((const float4*)in)[(size_t)n * (K / 4) + kq];
            if constexpr (RELU_BIAS) {
                float4 b = ((const float4*)bias)[kq];
                v.x = fmaxf(v.x + b.x, 0.f);
                v.y = fmaxf(v.y + b.y, 0.f);
                v.z = fmaxf(v.z + b.z, 0.f);
                v.w = fmaxf(v.w + b.w, 0.f);
            }
            *(float4*)&xs[ni * KP + kq * 4] = v;
        }
    }
    __syncthreads();

    const int tx = tid % FT;
    const int tg = tid / FT;
    if (tg >= TG) return;

    float4 acc[NPT];
    #pragma unroll
    for (int i = 0; i < NPT; ++i) acc[i] = make_float4(0.f, 0.f, 0.f, 0.f);

    #pragma unroll 4
    for (int kq = 0; kq < K / 4; ++kq) {
        float4 w0 = *(const float4*)&Ws[(kq * 4 + 0) * F + tx * 4];
        float4 w1 = *(const float4*)&Ws[(kq * 4 + 1) * F + tx * 4];
        float4 w2 = *(const float4*)&Ws[(kq * 4 + 2) * F + tx * 4];
        float4 w3 = *(const float4*)&Ws[(kq * 4 + 3) * F + tx * 4];
        #pragma unroll
        for (int i = 0; i < NPT; ++i) {
            float4 xv = *(const float4*)&xs[(tg * NPT + i) * KP + kq * 4];
            acc[i].x += xv.x * w0.x + xv.y * w1.x + xv.z * w2.x + xv.w * w3.x;
            acc[i].y += xv.x * w0.y + xv.y * w1.y + xv.z * w2.y + xv.w * w3.y;
            acc[i].z += xv.x * w0.z + xv.y * w1.z + xv.z * w2.z + xv.w * w3.z;
            acc[i].w += xv.x * w0.w + xv.y * w1.w + xv.z * w2.w + xv.w * w3.w;
        }
    }

    #pragma unroll
    for (int i = 0; i < NPT; ++i) {
        int n = n0 + tg * NPT + i;
        if (n < N) {
            float d = dinv[n];
            ushort4 o;
            o.x = fbf(acc[i].x * d);
            o.y = fbf(acc[i].y * d);
            o.z = fbf(acc[i].z * d);
            o.w = fbf(acc[i].w * d);
            if constexpr (OUT2) {
                int p = tx >> 3;             // feature f = tx*4 -> plane tx>>3
                int col = (tx & 7) * 4;
                *(ushort4*)(out + p * PS + (size_t)n * 32 + col) = o;
            } else {
                *(ushort4*)(out + (size_t)n * F + tx * 4) = o;
            }
        }
    }
}

// ======================= plane gather: 32 features, 8 edges per wave-instr =======================
// One wave per dst node per plane dispatch. lanes = 8 groups x 8 feature-quads;
// lane loads uint2 (4 bf16) of its group's source row-slice. Working set per
// dispatch = one 6.4 MB plane -> higher L2 hit rate than a 12.8 MB full row.

__launch_bounds__(256)
__global__ void gather32p(const unsigned short* __restrict__ g, const float* __restrict__ dinv,
                          const int* __restrict__ row_ptr, const int* __restrict__ csr_src,
                          unsigned short* __restrict__ outp, int N) {
    int gid = blockIdx.x * blockDim.x + threadIdx.x;
    int n = gid >> 6;
    if (n >= N) return;
    int lane = gid & 63;
    const int grp = lane >> 3;          // edge slot 0..7
    const int fq  = lane & 7;           // features fq*4..fq*4+3

    int e0 = row_ptr[n], e1 = row_ptr[n + 1];

    float4 acc = make_float4(0.f, 0.f, 0.f, 0.f);
    {
        uint2 u = *(const uint2*)(g + (size_t)n * 32 + fq * 4);   // self loop
        if (grp == 0) acc = up4(u);
    }

    int e = e0;
    for (; e + 16 <= e1; e += 16) {     // two independent 8-edge chains
        int sA = csr_src[e + grp];
        int sB = csr_src[e + 8 + grp];
        uint2 uA = *(const uint2*)(g + (size_t)sA * 32 + fq * 4);
        uint2 uB = *(const uint2*)(g + (size_t)sB * 32 + fq * 4);
        float4 a = up4(uA), b = up4(uB);
        acc.x += a.x + b.x; acc.y += a.y + b.y;
        acc.z += a.z + b.z; acc.w += a.w + b.w;
    }
    if (e + 8 <= e1) {
        int s = csr_src[e + grp];
        uint2 u = *(const uint2*)(g + (size_t)s * 32 + fq * 4);
        float4 a = up4(u);
        acc.x += a.x; acc.y += a.y; acc.z += a.z; acc.w += a.w;
        e += 8;
    }
    int m = e1 - e;                     // 0..7
    if (m > 0) {
        int s = csr_src[(e + grp < e1) ? e + grp : e1 - 1];
        uint2 u = *(const uint2*)(g + (size_t)s * 32 + fq * 4);
        if (grp < m) {
            float4 a = up4(u);
            acc.x += a.x; acc.y += a.y; acc.z += a.z; acc.w += a.w;
        }
    }

    // combine 8 group partials (same fq at lanes fq, fq+8, ..., fq+56)
    #pragma unroll
    for (int off = 8; off <= 32; off <<= 1) {
        acc.x += __shfl_xor(acc.x, off, 64);
        acc.y += __shfl_xor(acc.y, off, 64);
        acc.z += __shfl_xor(acc.z, off, 64);
        acc.w += __shfl_xor(acc.w, off, 64);
    }

    if (grp == 0) {
        float d = dinv[n];
        ushort4 o;
        o.x = fbf(acc.x * d); o.y = fbf(acc.y * d);
        o.z = fbf(acc.z * d); o.w = fbf(acc.w * d);
        *(ushort4*)(outp + (size_t)n * 32 + fq * 4) = o;
    }
}

// Layer-3: wide gather on 40-wide rows + fused bias + log_softmax.
// fq clamped to 0..9 so no lane fetches beyond the 80B row (junk quads were
// costing ~20MB of extra FETCH in round 6).
__launch_bounds__(256)
__global__ void gather40w_lsm(const unsigned short* __restrict__ g, const float* __restrict__ dinv,
                              const int* __restrict__ row_ptr, const int* __restrict__ csr_src,
                              const float* __restrict__ b3, float* __restrict__ out, int N) {
    int gid = blockIdx.x * blockDim.x + threadIdx.x;
    int n = gid >> 6;
    if (n >= N) return;
    int lane = gid & 63;
    const int grp = lane >> 4;          // edge slot 0..3
    const int fq  = lane & 15;          // logical quad
    const int fqc = min(fq, 9);         // clamped: lanes fq>=10 duplicate quad 9 (same line)

    int e0 = row_ptr[n], e1 = row_ptr[n + 1];

    float4 acc = make_float4(0.f, 0.f, 0.f, 0.f);
    {
        uint2 u = *(const uint2*)(g + (size_t)n * NCLASS + fqc * 4);
        if (grp == 0) acc = up4(u);
    }

    int e = e0;
    for (; e + 8 <= e1; e += 8) {
        int sA = csr_src[e + grp];
        int sB = csr_src[e + 4 + grp];
        uint2 uA = *(const uint2*)(g + (size_t)sA * NCLASS + fqc * 4);
        uint2 uB = *(const uint2*)(g + (size_t)sB * NCLASS + fqc * 4);
        float4 a = up4(uA), b = up4(uB);
        acc.x += a.x + b.x; acc.y += a.y + b.y;
        acc.z += a.z + b.z; acc.w += a.w + b.w;
    }
    if (e + 4 <= e1) {
        int s = csr_src[e + grp];
        uint2 u = *(const uint2*)(g + (size_t)s * NCLASS + fqc * 4);
        float4 a = up4(u);
        acc.x += a.x; acc.y += a.y; acc.z += a.z; acc.w += a.w;
        e += 4;
    }
    int m = e1 - e;
    if (m > 0) {
        int s = csr_src[(e + grp < e1) ? e + grp : e1 - 1];
        uint2 u = *(const uint2*)(g + (size_t)s * NCLASS + fqc * 4);
        if (grp < m) {
            float4 a = up4(u);
            acc.x += a.x; acc.y += a.y; acc.z += a.z; acc.w += a.w;
        }
    }

    #pragma unroll
    for (int off = 16; off <= 32; off <<= 1) {
        acc.x += __shfl_xor(acc.x, off, 64);
        acc.y += __shfl_xor(acc.y, off, 64);
        acc.z += __shfl_xor(acc.z, off, 64);
        acc.w += __shfl_xor(acc.w, off, 64);
    }

    // bias + log_softmax over 40 classes; quads >= 10 masked out
    float d = dinv[n];
    float4 b = *(const float4*)(b3 + fqc * 4);
    float4 v = make_float4(acc.x * d + b.x, acc.y * d + b.y,
                           acc.z * d + b.z, acc.w * d + b.w);
    float lm = (fq < 10) ? fmaxf(fmaxf(v.x, v.y), fmaxf(v.z, v.w)) : -1e30f;
    #pragma unroll
    for (int off = 1; off < 16; off <<= 1)
        lm = fmaxf(lm, __shfl_xor(lm, off, 64));
    float ls = (fq < 10) ? (expf(v.x - lm) + expf(v.y - lm) + expf(v.z - lm) + expf(v.w - lm)) : 0.f;
    #pragma unroll
    for (int off = 1; off < 16; off <<= 1)
        ls += __shfl_xor(ls, off, 64);
    float lg = lm + logf(ls);
    if (grp == 0 && fq < 10) {
        float4 o = make_float4(v.x - lg, v.y - lg, v.z - lg, v.w - lg);
        *(float4*)(out + (size_t)n * NCLASS + fq * 4) = o;
    }
}

// ======================= launch =======================

extern "C" void kernel_launch(void* const* d_in, const int* in_sizes, int n_in,
                              void* d_out, int out_size, void* d_ws, size_t ws_size,
                              hipStream_t stream) {
    const float* x  = (const float*)d_in[0];
    const int*   ei = (const int*)  d_in[1];
    const float* W1 = (const float*)d_in[2];
    const float* b1 = (const float*)d_in[3];
    const float* W2 = (const float*)d_in[4];
    const float* b2 = (const float*)d_in[5];
    const float* W3 = (const float*)d_in[6];
    const float* b3 = (const float*)d_in[7];
    const int N = in_sizes[0] / NFEAT;
    const int E = in_sizes[1] / 2;
    const int* src = ei;
    const int* dst = ei + E;
    float* out = (float*)d_out;

    const int nbin = (N + (1 << BSH) - 1) >> BSH;          // 391

    // ---- workspace layout (4-byte units, 256-aligned sections) ----
    const size_t Np = ((size_t)N + 256) & ~(size_t)255;
    const size_t Ep = ((size_t)E + 255) & ~(size_t)255;
    const size_t Fp = (((size_t)N * 32) + 255) & ~(size_t)255;   // N*64 bf16 in floats
    float* base = (float*)d_ws;
    size_t off = 0;
    int*      gcount  = (int*)(base + off);  off += MAXBIN;
    int*      gbase   = (int*)(base + off);  off += MAXBIN + 256;
    int*      gcur    = (int*)(base + off);  off += MAXBIN;
    int*      row_ptr = (int*)(base + off);  off += Np;
    float*    dinv    =        base + off;   off += Np;
    unsigned* ebuf    = (unsigned*)(base + off); off += Ep;
    int*      csr_src = (int*)(base + off);  off += Ep;
    unsigned short* tb = (unsigned short*)(base + off); off += Fp;
    unsigned short* ab = (unsigned short*)(base + off); off += Fp;
    // total ~ 39 MB

    const size_t PS = (size_t)N * 32;                      // plane stride (bf16 elems)
    const int nchunk = (E + CH - 1) / CH;                  // 784

    // ---- CSR build (also produces dinv) ----
    hipMemsetAsync(gcount, 0, MAXBIN * sizeof(int), stream);
    binA1<<<nchunk, 256, 0, stream>>>(dst, gcount, E, nbin);
    binscan<<<1, 512, 0, stream>>>(gcount, gbase, gcur, row_ptr, nbin, N, E);
    binA2<<<nchunk, 256, 0, stream>>>(src, dst, gcur, ebuf, E, nbin);
    binB<<<nbin, 256, 0, stream>>>(ebuf, gbase, row_ptr, dinv, csr_src, N);

    const int gatherBlocks = (int)(((size_t)N * 64 + 255) / 256);

    // ---- layer 1 ----
    lin_kernel<NFEAT, NHID, false, false, true><<<(N + 63) / 64, 256, 0, stream>>>(x, W1, nullptr, dinv, tb, N);
    gather32p<<<gatherBlocks, 256, 0, stream>>>(tb, dinv, row_ptr, csr_src, ab, N);
    gather32p<<<gatherBlocks, 256, 0, stream>>>(tb + PS, dinv, row_ptr, csr_src, ab + PS, N);

    // ---- layer 2 ----
    lin_kernel<NHID, NHID, true, true, true><<<(N + 63) / 64, 256, 0, stream>>>(ab, W2, b1, dinv, tb, N);
    gather32p<<<gatherBlocks, 256, 0, stream>>>(tb, dinv, row_ptr, csr_src, ab, N);
    gather32p<<<gatherBlocks, 256, 0, stream>>>(tb + PS, dinv, row_ptr, csr_src, ab + PS, N);

    // ---- layer 3 ----
    lin_kernel<NHID, NCLASS, true, true, false><<<(N + 99) / 100, 256, 0, stream>>>(ab, W3, b2, dinv, tb, N);
    gather40w_lsm<<<gatherBlocks, 256, 0, stream>>>(tb, dinv, row_ptr, csr_src, b3, out, N);
}

// Round 8
// 432.354 us; speedup vs baseline: 1.0224x; 1.0224x over previous
//
#include <hip/hip_runtime.h>

#define NFEAT 128
#define NHID 64
#define NCLASS 40

#define BSH 8                    // CSR-build bin = 256 nodes
#define MAXBIN 512               // supports N <= 131072
#define CH 2048                  // edges per chunk in pass A

// ---------------- bf16 helpers (storage-only precision; compute is fp32) ----------------

__device__ __forceinline__ float bfu(unsigned short u) {
    return __uint_as_float((unsigned)u << 16);
}
__device__ __forceinline__ unsigned short fbf(float f) {
    unsigned u = __float_as_uint(f);
    u += 0x7fffu + ((u >> 16) & 1u);        // round-to-nearest-even
    return (unsigned short)(u >> 16);
}
// unpack uint2 (4 packed bf16) -> float4 ; all-zero input -> 0.0f (used for masking)
__device__ __forceinline__ float4 up4(uint2 u) {
    return make_float4(__uint_as_float(u.x << 16), __uint_as_float(u.x & 0xffff0000u),
                       __uint_as_float(u.y << 16), __uint_as_float(u.y & 0xffff0000u));
}

// ======================= CSR build, hierarchical =======================

__launch_bounds__(256)
__global__ void binA1(const int* __restrict__ dst, int* __restrict__ gcount, int E, int nbin) {
    __shared__ int h[MAXBIN];
    const int t = threadIdx.x;
    for (int i = t; i < nbin; i += 256) h[i] = 0;
    __syncthreads();
    const int e0 = blockIdx.x * CH;
    const int e1 = min(e0 + CH, E);
    for (int i = e0 + t; i < e1; i += 256) atomicAdd(&h[dst[i] >> BSH], 1);
    __syncthreads();
    for (int i = t; i < nbin; i += 256) { int c = h[i]; if (c) atomicAdd(&gcount[i], c); }
}

__launch_bounds__(512)
__global__ void binscan(const int* __restrict__ gcount, int* __restrict__ gbase,
                        int* __restrict__ gcur, int* __restrict__ row_ptr,
                        int nbin, int N, int E) {
    __shared__ int sd[512];
    const int t = threadIdx.x;
    int v = (t < nbin) ? gcount[t] : 0;
    sd[t] = v;
    __syncthreads();
    for (int off = 1; off < 512; off <<= 1) {
        int tmp = (t >= off) ? sd[t - off] : 0;
        __syncthreads();
        sd[t] += tmp;
        __syncthreads();
    }
    int excl = sd[t] - v;
    if (t < nbin) { gbase[t] = excl; gcur[t] = excl; }
    if (t == 0) { gbase[nbin] = E; row_ptr[N] = E; }
}

// A2: reserve a contiguous run per bin, scatter packed (local_dst<<24 | src).
__launch_bounds__(256)
__global__ void binA2(const int* __restrict__ src, const int* __restrict__ dst,
                      int* __restrict__ gcur, unsigned* __restrict__ ebuf, int E, int nbin) {
    __shared__ int h[MAXBIN];
    __shared__ int base[MAXBIN];
    const int t = threadIdx.x;
    for (int i = t; i < nbin; i += 256) h[i] = 0;
    __syncthreads();
    const int e0 = blockIdx.x * CH;
    const int e1 = min(e0 + CH, E);
    for (int i = e0 + t; i < e1; i += 256) atomicAdd(&h[dst[i] >> BSH], 1);
    __syncthreads();
    for (int i = t; i < nbin; i += 256) {
        int c = h[i];
        if (c) base[i] = atomicAdd(&gcur[i], c);
        h[i] = 0;
    }
    __syncthreads();
    for (int i = e0 + t; i < e1; i += 256) {
        int d = dst[i];
        int b = d >> BSH;
        int pos = base[b] + atomicAdd(&h[b], 1);
        ebuf[pos] = ((unsigned)(d & ((1 << BSH) - 1)) << 24) | (unsigned)src[i];
    }
}

// B: one wg per 256-node bin: LDS count -> scan -> row_ptr + dinv + csr scatter.
__launch_bounds__(256)
__global__ void binB(const unsigned* __restrict__ ebuf, const int* __restrict__ gbase,
                     int* __restrict__ row_ptr, float* __restrict__ dinv,
                     int* __restrict__ csr_src, int N) {
    __shared__ int cnt[256];
    __shared__ int sd[256];
    __shared__ int cur[256];
    const int b = blockIdx.x;
    const int n0 = b << BSH;
    const int t = threadIdx.x;
    const int b0 = gbase[b], b1 = gbase[b + 1];
    cnt[t] = 0;
    __syncthreads();
    for (int i = b0 + t; i < b1; i += 256) atomicAdd(&cnt[ebuf[i] >> 24], 1);
    __syncthreads();
    int v = cnt[t];
    sd[t] = v;
    __syncthreads();
    for (int off = 1; off < 256; off <<= 1) {
        int tmp = (t >= off) ? sd[t - off] : 0;
        __syncthreads();
        sd[t] += tmp;
        __syncthreads();
    }
    int excl = sd[t] - v;
    int n = n0 + t;
    if (n < N) {
        row_ptr[n] = b0 + excl;
        dinv[n] = rsqrtf((float)v + 1.0f);      // +1 self loop
    }
    cur[t] = b0 + excl;
    __syncthreads();
    for (int i = b0 + t; i < b1; i += 256) {
        unsigned p = ebuf[i];
        int pos = atomicAdd(&cur[p >> 24], 1);
        csr_src[pos] = (int)(p & 0xffffffu);
    }
}

// ======================= layer-1 dense linear (fp32 in, bf16 out) =======================
// out[n,:] = bf16( dinv[n] * (x[n,:] @ W1) )

__launch_bounds__(256)
__global__ void lin1_kernel(const float* __restrict__ in, const float* __restrict__ W,
                            const float* __restrict__ dinv,
                            unsigned short* __restrict__ out, int N) {
    constexpr int K = NFEAT;             // 128
    constexpr int F = NHID;              // 64
    constexpr int FT = F / 4;            // 16
    constexpr int TG = 256 / FT;         // 16
    constexpr int NPT = 4;
    constexpr int NODES = 64;
    constexpr int KP = K + 4;

    __shared__ alignas(16) float Ws[K * F];
    __shared__ alignas(16) float xs[NODES * KP];

    const int tid = threadIdx.x;
    const int n0 = blockIdx.x * NODES;

    for (int q = tid; q < K * F / 4; q += 256)
        ((float4*)Ws)[q] = ((const float4*)W)[q];

    for (int q = tid; q < NODES * (K / 4); q += 256) {
        int ni = q / (K / 4);
        int kq = q - ni * (K / 4);
        int n = n0 + ni;
        float4 v = make_float4(0.f, 0.f, 0.f, 0.f);
        if (n < N) v = ((const float4*)in)[(size_t)n * (K / 4) + kq];
        *(float4*)&xs[ni * KP + kq * 4] = v;
    }
    __syncthreads();

    const int tx = tid % FT;
    const int tg = tid / FT;

    float4 acc[NPT];
    #pragma unroll
    for (int i = 0; i < NPT; ++i) acc[i] = make_float4(0.f, 0.f, 0.f, 0.f);

    #pragma unroll 4
    for (int kq = 0; kq < K / 4; ++kq) {
        float4 w0 = *(const float4*)&Ws[(kq * 4 + 0) * F + tx * 4];
        float4 w1 = *(const float4*)&Ws[(kq * 4 + 1) * F + tx * 4];
        float4 w2 = *(const float4*)&Ws[(kq * 4 + 2) * F + tx * 4];
        float4 w3 = *(const float4*)&Ws[(kq * 4 + 3) * F + tx * 4];
        #pragma unroll
        for (int i = 0; i < NPT; ++i) {
            float4 xv = *(const float4*)&xs[(tg * NPT + i) * KP + kq * 4];
            acc[i].x += xv.x * w0.x + xv.y * w1.x + xv.z * w2.x + xv.w * w3.x;
            acc[i].y += xv.x * w0.y + xv.y * w1.y + xv.z * w2.y + xv.w * w3.y;
            acc[i].z += xv.x * w0.z + xv.y * w1.z + xv.z * w2.z + xv.w * w3.z;
            acc[i].w += xv.x * w0.w + xv.y * w1.w + xv.z * w2.w + xv.w * w3.w;
        }
    }

    #pragma unroll
    for (int i = 0; i < NPT; ++i) {
        int n = n0 + tg * NPT + i;
        if (n < N) {
            float d = dinv[n];
            ushort4 o;
            o.x = fbf(acc[i].x * d);
            o.y = fbf(acc[i].y * d);
            o.z = fbf(acc[i].z * d);
            o.w = fbf(acc[i].w * d);
            *(ushort4*)(out + (size_t)n * F + tx * 4) = o;
        }
    }
}

// ======================= fused gather + linear =======================
// Per block of NODES dst nodes:
//   phase G: gather a[n,:] = dinv[n]*(g[n,:] + sum_{s in N(n)} g[s,:]) and write
//            xs[n,:] = relu(a + bias_prev) into LDS (4 node-slots x 16 fq lanes
//            per wave; 4-edge masked unroll -> 8 rows in flight per wave).
//   phase L: xs @ W -> out (bf16, pre-scaled by dinv for the NEXT gather).
// Gather-phase waves of co-resident blocks overlap with GEMM-phase waves, so
// the GEMM rides under the gather's L2-miss latency (the measured ~2.1 TB/s
// MSHR wall) instead of costing its own dispatch.

template<int F, int NODES>
__launch_bounds__(256)
__global__ void fused_gather_lin(const unsigned short* __restrict__ gin,
                                 const float* __restrict__ dinv,
                                 const int* __restrict__ row_ptr,
                                 const int* __restrict__ csr_src,
                                 const float* __restrict__ W,      // [64][F]
                                 const float* __restrict__ bias,   // [64], prev layer
                                 unsigned short* __restrict__ out, // [N][F]
                                 int N) {
    constexpr int K = 64;
    constexpr int KP = K + 4;
    constexpr int FT = F / 4;            // 16 or 10
    constexpr int TG = 256 / FT;         // 16 or 25
    constexpr int NPT = NODES / TG;      // 4
    constexpr int PW = NODES / 4;        // nodes per wave: 16 or 25

    __shared__ alignas(16) float Ws[K * F];
    __shared__ alignas(16) float xs[NODES * KP];

    const int tid = threadIdx.x;
    const int n0 = blockIdx.x * NODES;

    // stage W (completes under the gather; consumed after the barrier)
    for (int q = tid; q < K * F / 4; q += 256)
        ((float4*)Ws)[q] = ((const float4*)W)[q];

    // ---- phase G ----
    const int w = tid >> 6;
    const int lane = tid & 63;
    const int grp = lane >> 4;           // node slot 0..3
    const int fq = lane & 15;            // feature quad 0..15 (covers 64 input feats)
    const float4 bq = *(const float4*)(bias + fq * 4);

    for (int r = 0; r * 4 < PW; ++r) {
        const int nli = r * 4 + grp;     // index within this wave's node set
        const int nl = w * PW + nli;     // local node in block
        const int n = n0 + nl;
        const bool valid = (nli < PW) && (n < N);
        float4 acc = make_float4(0.f, 0.f, 0.f, 0.f);
        int e = 0, e1 = 0;
        if (valid) {
            e = row_ptr[n];
            e1 = row_ptr[n + 1];
            uint2 u = *(const uint2*)(gin + (size_t)n * 64 + fq * 4);   // self loop
            acc = up4(u);
        }
        while (__any(e < e1)) {
            uint2 u0 = make_uint2(0u, 0u), u1 = make_uint2(0u, 0u);
            uint2 u2 = make_uint2(0u, 0u), u3 = make_uint2(0u, 0u);
            if (e < e1)     u0 = *(const uint2*)(gin + (size_t)csr_src[e]     * 64 + fq * 4);
            if (e + 1 < e1) u1 = *(const uint2*)(gin + (size_t)csr_src[e + 1] * 64 + fq * 4);
            if (e + 2 < e1) u2 = *(const uint2*)(gin + (size_t)csr_src[e + 2] * 64 + fq * 4);
            if (e + 3 < e1) u3 = *(const uint2*)(gin + (size_t)csr_src[e + 3] * 64 + fq * 4);
            float4 f0 = up4(u0), f1 = up4(u1), f2 = up4(u2), f3 = up4(u3);
            acc.x += (f0.x + f1.x) + (f2.x + f3.x);
            acc.y += (f0.y + f1.y) + (f2.y + f3.y);
            acc.z += (f0.z + f1.z) + (f2.z + f3.z);
            acc.w += (f0.w + f1.w) + (f2.w + f3.w);
            e += 4;
        }
        if (valid) {
            float d = dinv[n];
            float4 v;
            v.x = fmaxf(acc.x * d + bq.x, 0.f);
            v.y = fmaxf(acc.y * d + bq.y, 0.f);
            v.z = fmaxf(acc.z * d + bq.z, 0.f);
            v.w = fmaxf(acc.w * d + bq.w, 0.f);
            *(float4*)&xs[nl * KP + fq * 4] = v;
        }
    }
    __syncthreads();

    // ---- phase L ----
    const int tx = tid % FT;
    const int tg = tid / FT;
    if (tg >= TG) return;                // F=40: threads 250..255 idle here

    float4 acc[NPT];
    #pragma unroll
    for (int i = 0; i < NPT; ++i) acc[i] = make_float4(0.f, 0.f, 0.f, 0.f);

    #pragma unroll 4
    for (int kq = 0; kq < K / 4; ++kq) {
        float4 w0 = *(const float4*)&Ws[(kq * 4 + 0) * F + tx * 4];
        float4 w1 = *(const float4*)&Ws[(kq * 4 + 1) * F + tx * 4];
        float4 w2 = *(const float4*)&Ws[(kq * 4 + 2) * F + tx * 4];
        float4 w3 = *(const float4*)&Ws[(kq * 4 + 3) * F + tx * 4];
        #pragma unroll
        for (int i = 0; i < NPT; ++i) {
            float4 xv = *(const float4*)&xs[(tg * NPT + i) * KP + kq * 4];
            acc[i].x += xv.x * w0.x + xv.y * w1.x + xv.z * w2.x + xv.w * w3.x;
            acc[i].y += xv.x * w0.y + xv.y * w1.y + xv.z * w2.y + xv.w * w3.y;
            acc[i].z += xv.x * w0.z + xv.y * w1.z + xv.z * w2.z + xv.w * w3.z;
            acc[i].w += xv.x * w0.w + xv.y * w1.w + xv.z * w2.w + xv.w * w3.w;
        }
    }

    #pragma unroll
    for (int i = 0; i < NPT; ++i) {
        int n = n0 + tg * NPT + i;
        if (n < N) {
            float d = dinv[n];
            ushort4 o;
            o.x = fbf(acc[i].x * d);
            o.y = fbf(acc[i].y * d);
            o.z = fbf(acc[i].z * d);
            o.w = fbf(acc[i].w * d);
            *(ushort4*)(out + (size_t)n * F + tx * 4) = o;
        }
    }
}

// ======================= final gather (40-wide) + bias + log_softmax =======================
// fq clamped to 0..9 so no lane fetches beyond the 80B row.

__launch_bounds__(256)
__global__ void gather40w_lsm(const unsigned short* __restrict__ g, const float* __restrict__ dinv,
                              const int* __restrict__ row_ptr, const int* __restrict__ csr_src,
                              const float* __restrict__ b3, float* __restrict__ out, int N) {
    int gid = blockIdx.x * blockDim.x + threadIdx.x;
    int n = gid >> 6;
    if (n >= N) return;
    int lane = gid & 63;
    const int grp = lane >> 4;          // edge slot 0..3
    const int fq  = lane & 15;
    const int fqc = min(fq, 9);         // lanes fq>=10 duplicate quad 9 (same line)

    int e0 = row_ptr[n], e1 = row_ptr[n + 1];

    float4 acc = make_float4(0.f, 0.f, 0.f, 0.f);
    {
        uint2 u = *(const uint2*)(g + (size_t)n * NCLASS + fqc * 4);
        if (grp == 0) acc = up4(u);
    }

    int e = e0;
    for (; e + 8 <= e1; e += 8) {
        int sA = csr_src[e + grp];
        int sB = csr_src[e + 4 + grp];
        uint2 uA = *(const uint2*)(g + (size_t)sA * NCLASS + fqc * 4);
        uint2 uB = *(const uint2*)(g + (size_t)sB * NCLASS + fqc * 4);
        float4 a = up4(uA), b = up4(uB);
        acc.x += a.x + b.x; acc.y += a.y + b.y;
        acc.z += a.z + b.z; acc.w += a.w + b.w;
    }
    if (e + 4 <= e1) {
        int s = csr_src[e + grp];
        uint2 u = *(const uint2*)(g + (size_t)s * NCLASS + fqc * 4);
        float4 a = up4(u);
        acc.x += a.x; acc.y += a.y; acc.z += a.z; acc.w += a.w;
        e += 4;
    }
    int m = e1 - e;
    if (m > 0) {
        int s = csr_src[(e + grp < e1) ? e + grp : e1 - 1];
        uint2 u = *(const uint2*)(g + (size_t)s * NCLASS + fqc * 4);
        if (grp < m) {
            float4 a = up4(u);
            acc.x += a.x; acc.y += a.y; acc.z += a.z; acc.w += a.w;
        }
    }

    #pragma unroll
    for (int off = 16; off <= 32; off <<= 1) {
        acc.x += __shfl_xor(acc.x, off, 64);
        acc.y += __shfl_xor(acc.y, off, 64);
        acc.z += __shfl_xor(acc.z, off, 64);
        acc.w += __shfl_xor(acc.w, off, 64);
    }

    float d = dinv[n];
    float4 b = *(const float4*)(b3 + fqc * 4);
    float4 v = make_float4(acc.x * d + b.x, acc.y * d + b.y,
                           acc.z * d + b.z, acc.w * d + b.w);
    float lm = (fq < 10) ? fmaxf(fmaxf(v.x, v.y), fmaxf(v.z, v.w)) : -1e30f;
    #pragma unroll
    for (int off = 1; off < 16; off <<= 1)
        lm = fmaxf(lm, __shfl_xor(lm, off, 64));
    float ls = (fq < 10) ? (expf(v.x - lm) + expf(v.y - lm) + expf(v.z - lm) + expf(v.w - lm)) : 0.f;
    #pragma unroll
    for (int off = 1; off < 16; off <<= 1)
        ls += __shfl_xor(ls, off, 64);
    float lg = lm + logf(ls);
    if (grp == 0 && fq < 10) {
        float4 o = make_float4(v.x - lg, v.y - lg, v.z - lg, v.w - lg);
        *(float4*)(out + (size_t)n * NCLASS + fq * 4) = o;
    }
}

// ======================= launch =======================

extern "C" void kernel_launch(void* const* d_in, const int* in_sizes, int n_in,
                              void* d_out, int out_size, void* d_ws, size_t ws_size,
                              hipStream_t stream) {
    const float* x  = (const float*)d_in[0];
    const int*   ei = (const int*)  d_in[1];
    const float* W1 = (const float*)d_in[2];
    const float* b1 = (const float*)d_in[3];
    const float* W2 = (const float*)d_in[4];
    const float* b2 = (const float*)d_in[5];
    const float* W3 = (const float*)d_in[6];
    const float* b3 = (const float*)d_in[7];
    const int N = in_sizes[0] / NFEAT;
    const int E = in_sizes[1] / 2;
    const int* src = ei;
    const int* dst = ei + E;
    float* out = (float*)d_out;

    const int nbin = (N + (1 << BSH) - 1) >> BSH;          // 391

    // ---- workspace layout (4-byte units, 256-aligned sections) ----
    const size_t Np = ((size_t)N + 256) & ~(size_t)255;
    const size_t Ep = ((size_t)E + 255) & ~(size_t)255;
    const size_t Fp = (((size_t)N * 32) + 255) & ~(size_t)255;   // N*64 bf16 in floats
    float* base = (float*)d_ws;
    size_t off = 0;
    int*      gcount  = (int*)(base + off);  off += MAXBIN;
    int*      gbase   = (int*)(base + off);  off += MAXBIN + 256;
    int*      gcur    = (int*)(base + off);  off += MAXBIN;
    int*      row_ptr = (int*)(base + off);  off += Np;
    float*    dinv    =        base + off;   off += Np;
    unsigned* ebuf    = (unsigned*)(base + off); off += Ep;
    int*      csr_src = (int*)(base + off);  off += Ep;
    unsigned short* tb = (unsigned short*)(base + off); off += Fp;  // g1, then g3 (40-wide)
    unsigned short* ab = (unsigned short*)(base + off); off += Fp;  // g2
    // total ~ 39 MB

    const int nchunk = (E + CH - 1) / CH;

    // ---- CSR build (also produces dinv) ----
    hipMemsetAsync(gcount, 0, MAXBIN * sizeof(int), stream);
    binA1<<<nchunk, 256, 0, stream>>>(dst, gcount, E, nbin);
    binscan<<<1, 512, 0, stream>>>(gcount, gbase, gcur, row_ptr, nbin, N, E);
    binA2<<<nchunk, 256, 0, stream>>>(src, dst, gcur, ebuf, E, nbin);
    binB<<<nbin, 256, 0, stream>>>(ebuf, gbase, row_ptr, dinv, csr_src, N);

    // ---- layer 1: g1 = dinv * (x @ W1) ----
    lin1_kernel<<<(N + 63) / 64, 256, 0, stream>>>(x, W1, dinv, tb, N);

    // ---- layer 2 fused: g2 = dinv * ( relu(gather(g1)*dinv + b1) @ W2 ) ----
    fused_gather_lin<NHID, 64><<<(N + 63) / 64, 256, 0, stream>>>(
        tb, dinv, row_ptr, csr_src, W2, b1, ab, N);

    // ---- layer 3 fused: g3 = dinv * ( relu(gather(g2)*dinv + b2) @ W3 ) ----
    fused_gather_lin<NCLASS, 100><<<(N + 99) / 100, 256, 0, stream>>>(
        ab, dinv, row_ptr, csr_src, W3, b2, tb, N);

    // ---- final gather + bias + log_softmax ----
    const int gatherBlocks = (int)(((size_t)N * 64 + 255) / 256);
    gather40w_lsm<<<gatherBlocks, 256, 0, stream>>>(tb, dinv, row_ptr, csr_src, b3, out, N);
}

// Round 9
// 399.072 us; speedup vs baseline: 1.1076x; 1.0834x over previous
//
#include <hip/hip_runtime.h>

#define NFEAT 128
#define NHID 64
#define NCLASS 40

#define BSH 8                    // CSR-build bin = 256 nodes
#define MAXBIN 512               // supports N <= 131072
#define CH 8192                  // edges per chunk in pass A

// ---------------- bf16 helpers (storage-only precision; compute is fp32) ----------------

__device__ __forceinline__ float bfu(unsigned short u) {
    return __uint_as_float((unsigned)u << 16);
}
__device__ __forceinline__ unsigned short fbf(float f) {
    unsigned u = __float_as_uint(f);
    u += 0x7fffu + ((u >> 16) & 1u);        // round-to-nearest-even
    return (unsigned short)(u >> 16);
}
// unpack uint2 (4 packed bf16) -> float4 ; all-zero input -> 0.0f (used for masking)
__device__ __forceinline__ float4 up4(uint2 u) {
    return make_float4(__uint_as_float(u.x << 16), __uint_as_float(u.x & 0xffff0000u),
                       __uint_as_float(u.y << 16), __uint_as_float(u.y & 0xffff0000u));
}

// ======================= CSR build, hierarchical =======================

__launch_bounds__(256)
__global__ void binA1(const int* __restrict__ dst, int* __restrict__ gcount, int E, int nbin) {
    __shared__ int h[MAXBIN];
    const int t = threadIdx.x;
    for (int i = t; i < nbin; i += 256) h[i] = 0;
    __syncthreads();
    const int e0 = blockIdx.x * CH;
    const int e1 = min(e0 + CH, E);
    for (int i = e0 + t; i < e1; i += 256) atomicAdd(&h[dst[i] >> BSH], 1);
    __syncthreads();
    for (int i = t; i < nbin; i += 256) { int c = h[i]; if (c) atomicAdd(&gcount[i], c); }
}

__launch_bounds__(512)
__global__ void binscan(const int* __restrict__ gcount, int* __restrict__ gbase,
                        int* __restrict__ gcur, int* __restrict__ row_ptr,
                        int nbin, int N, int E) {
    __shared__ int sd[512];
    const int t = threadIdx.x;
    int v = (t < nbin) ? gcount[t] : 0;
    sd[t] = v;
    __syncthreads();
    for (int off = 1; off < 512; off <<= 1) {
        int tmp = (t >= off) ? sd[t - off] : 0;
        __syncthreads();
        sd[t] += tmp;
        __syncthreads();
    }
    int excl = sd[t] - v;
    if (t < nbin) { gbase[t] = excl; gcur[t] = excl; }
    if (t == 0) { gbase[nbin] = E; row_ptr[N] = E; }
}

// A2: reserve a contiguous run per bin, scatter packed (local_dst<<24 | src).
__launch_bounds__(256)
__global__ void binA2(const int* __restrict__ src, const int* __restrict__ dst,
                      int* __restrict__ gcur, unsigned* __restrict__ ebuf, int E, int nbin) {
    __shared__ int h[MAXBIN];
    __shared__ int base[MAXBIN];
    const int t = threadIdx.x;
    for (int i = t; i < nbin; i += 256) h[i] = 0;
    __syncthreads();
    const int e0 = blockIdx.x * CH;
    const int e1 = min(e0 + CH, E);
    for (int i = e0 + t; i < e1; i += 256) atomicAdd(&h[dst[i] >> BSH], 1);
    __syncthreads();
    for (int i = t; i < nbin; i += 256) {
        int c = h[i];
        if (c) base[i] = atomicAdd(&gcur[i], c);
        h[i] = 0;
    }
    __syncthreads();
    for (int i = e0 + t; i < e1; i += 256) {
        int d = dst[i];
        int b = d >> BSH;
        int pos = base[b] + atomicAdd(&h[b], 1);
        ebuf[pos] = ((unsigned)(d & ((1 << BSH) - 1)) << 24) | (unsigned)src[i];
    }
}

// B: one wg per 256-node bin: LDS count -> scan -> row_ptr + dinv + csr scatter.
__launch_bounds__(256)
__global__ void binB(const unsigned* __restrict__ ebuf, const int* __restrict__ gbase,
                     int* __restrict__ row_ptr, float* __restrict__ dinv,
                     int* __restrict__ csr_src, int N) {
    __shared__ int cnt[256];
    __shared__ int sd[256];
    __shared__ int cur[256];
    const int b = blockIdx.x;
    const int n0 = b << BSH;
    const int t = threadIdx.x;
    const int b0 = gbase[b], b1 = gbase[b + 1];
    cnt[t] = 0;
    __syncthreads();
    for (int i = b0 + t; i < b1; i += 256) atomicAdd(&cnt[ebuf[i] >> 24], 1);
    __syncthreads();
    int v = cnt[t];
    sd[t] = v;
    __syncthreads();
    for (int off = 1; off < 256; off <<= 1) {
        int tmp = (t >= off) ? sd[t - off] : 0;
        __syncthreads();
        sd[t] += tmp;
        __syncthreads();
    }
    int excl = sd[t] - v;
    int n = n0 + t;
    if (n < N) {
        row_ptr[n] = b0 + excl;
        dinv[n] = rsqrtf((float)v + 1.0f);      // +1 self loop
    }
    cur[t] = b0 + excl;
    __syncthreads();
    for (int i = b0 + t; i < b1; i += 256) {
        unsigned p = ebuf[i];
        int pos = atomicAdd(&cur[p >> 24], 1);
        csr_src[pos] = (int)(p & 0xffffffu);
    }
}

// ======================= layer-1 dense linear (fp32 in, bf16 out) =======================
// out[n,:] = bf16( dinv[n] * (x[n,:] @ W1) )

__launch_bounds__(256)
__global__ void lin1_kernel(const float* __restrict__ in, const float* __restrict__ W,
                            const float* __restrict__ dinv,
                            unsigned short* __restrict__ out, int N) {
    constexpr int K = NFEAT;             // 128
    constexpr int F = NHID;              // 64
    constexpr int FT = F / 4;            // 16
    constexpr int NPT = 4;
    constexpr int NODES = 64;
    constexpr int KP = K + 4;

    __shared__ alignas(16) float Ws[K * F];
    __shared__ alignas(16) float xs[NODES * KP];

    const int tid = threadIdx.x;
    const int n0 = blockIdx.x * NODES;

    for (int q = tid; q < K * F / 4; q += 256)
        ((float4*)Ws)[q] = ((const float4*)W)[q];

    for (int q = tid; q < NODES * (K / 4); q += 256) {
        int ni = q / (K / 4);
        int kq = q - ni * (K / 4);
        int n = n0 + ni;
        float4 v = make_float4(0.f, 0.f, 0.f, 0.f);
        if (n < N) v = ((const float4*)in)[(size_t)n * (K / 4) + kq];
        *(float4*)&xs[ni * KP + kq * 4] = v;
    }
    __syncthreads();

    const int tx = tid % FT;
    const int tg = tid / FT;

    float4 acc[NPT];
    #pragma unroll
    for (int i = 0; i < NPT; ++i) acc[i] = make_float4(0.f, 0.f, 0.f, 0.f);

    #pragma unroll 4
    for (int kq = 0; kq < K / 4; ++kq) {
        float4 w0 = *(const float4*)&Ws[(kq * 4 + 0) * F + tx * 4];
        float4 w1 = *(const float4*)&Ws[(kq * 4 + 1) * F + tx * 4];
        float4 w2 = *(const float4*)&Ws[(kq * 4 + 2) * F + tx * 4];
        float4 w3 = *(const float4*)&Ws[(kq * 4 + 3) * F + tx * 4];
        #pragma unroll
        for (int i = 0; i < NPT; ++i) {
            float4 xv = *(const float4*)&xs[(tg * NPT + i) * KP + kq * 4];
            acc[i].x += xv.x * w0.x + xv.y * w1.x + xv.z * w2.x + xv.w * w3.x;
            acc[i].y += xv.x * w0.y + xv.y * w1.y + xv.z * w2.y + xv.w * w3.y;
            acc[i].z += xv.x * w0.z + xv.y * w1.z + xv.z * w2.z + xv.w * w3.z;
            acc[i].w += xv.x * w0.w + xv.y * w1.w + xv.z * w2.w + xv.w * w3.w;
        }
    }

    #pragma unroll
    for (int i = 0; i < NPT; ++i) {
        int n = n0 + tg * NPT + i;
        if (n < N) {
            float d = dinv[n];
            ushort4 o;
            o.x = fbf(acc[i].x * d);
            o.y = fbf(acc[i].y * d);
            o.z = fbf(acc[i].z * d);
            o.w = fbf(acc[i].w * d);
            *(ushort4*)(out + (size_t)n * F + tx * 4) = o;
        }
    }
}

// ======================= fused gather + linear, v2 (high occupancy) =======================
// NODES=32 per block -> LDS 24.7 KB -> 6 blocks/CU = 24 waves/CU (r8 failed at
// ~10 waves). Phase G: 4 node-slots x 16 fq lanes per wave, 8-deep masked edge
// loads -> ~8 feature lines in flight per wave; 24 waves saturate the ~2.1 TB/s
// miss wall. Phase L: xs @ W (padded to 64 cols for F=40) -> bf16 out scaled by
// dinv for the next gather.

template<int F>                          // real output width: 64 or 40
__launch_bounds__(256)
__global__ void fused_gather_lin(const unsigned short* __restrict__ gin,
                                 const float* __restrict__ dinv,
                                 const int* __restrict__ row_ptr,
                                 const int* __restrict__ csr_src,
                                 const float* __restrict__ W,      // [64][F] row-major
                                 const float* __restrict__ bias,   // [64], prev layer
                                 unsigned short* __restrict__ out, // [N][F]
                                 int N) {
    constexpr int K = 64;
    constexpr int KP = K + 4;
    constexpr int NODES = 32;
    constexpr int FP = 64;               // padded compute width

    __shared__ alignas(16) float Ws[K * FP];   // 16 KB (zero-padded cols if F<64)
    __shared__ alignas(16) float xs[NODES * KP]; // 8.7 KB

    const int tid = threadIdx.x;
    const int n0 = blockIdx.x * NODES;

    // stage W (completes under the gather)
    if constexpr (F == 64) {
        for (int q = tid; q < K * FP / 4; q += 256)
            ((float4*)Ws)[q] = ((const float4*)W)[q];
    } else {
        for (int idx = tid; idx < K * FP; idx += 256) {
            int row = idx >> 6, col = idx & 63;
            Ws[idx] = (col < F) ? W[row * F + col] : 0.f;
        }
    }

    // ---- phase G: gather 32 nodes into xs ----
    const int w = tid >> 6;              // wave 0..3
    const int lane = tid & 63;
    const int grp = lane >> 4;           // node slot 0..3
    const int fq = lane & 15;            // feature quad (64 input feats)
    const float4 bq = *(const float4*)(bias + fq * 4);

    #pragma unroll
    for (int r = 0; r < 2; ++r) {        // 8 nodes/wave, 4 slots
        const int nl = w * 8 + r * 4 + grp;
        const int n = n0 + nl;
        const bool valid = (n < N);
        float4 acc = make_float4(0.f, 0.f, 0.f, 0.f);
        int e = 0, e1 = 0;
        float d = 0.f;
        if (valid) {
            e = row_ptr[n];
            e1 = row_ptr[n + 1];
            d = dinv[n];
            uint2 u = *(const uint2*)(gin + (size_t)n * 64 + fq * 4);   // self loop
            acc = up4(u);
        }
        while (__any(e < e1)) {
            uint2 u[8];
            #pragma unroll
            for (int k = 0; k < 8; ++k) {
                u[k] = make_uint2(0u, 0u);
                if (e + k < e1)
                    u[k] = *(const uint2*)(gin + (size_t)csr_src[e + k] * 64 + fq * 4);
            }
            #pragma unroll
            for (int k = 0; k < 8; ++k) {
                float4 f = up4(u[k]);
                acc.x += f.x; acc.y += f.y; acc.z += f.z; acc.w += f.w;
            }
            e += 8;
        }
        float4 v = make_float4(0.f, 0.f, 0.f, 0.f);
        if (valid) {
            v.x = fmaxf(acc.x * d + bq.x, 0.f);
            v.y = fmaxf(acc.y * d + bq.y, 0.f);
            v.z = fmaxf(acc.z * d + bq.z, 0.f);
            v.w = fmaxf(acc.w * d + bq.w, 0.f);
        }
        *(float4*)&xs[nl * KP + fq * 4] = v;
    }
    __syncthreads();

    // ---- phase L: xs[32][64] @ Ws[64][64] ----
    const int tx = tid & 15;             // output quad (padded 64-wide)
    const int tg = tid >> 4;             // 16 node groups, 2 nodes each

    float4 acc[2];
    acc[0] = make_float4(0.f, 0.f, 0.f, 0.f);
    acc[1] = make_float4(0.f, 0.f, 0.f, 0.f);

    #pragma unroll 4
    for (int kq = 0; kq < K / 4; ++kq) {
        float4 w0 = *(const float4*)&Ws[(kq * 4 + 0) * FP + tx * 4];
        float4 w1 = *(const float4*)&Ws[(kq * 4 + 1) * FP + tx * 4];
        float4 w2 = *(const float4*)&Ws[(kq * 4 + 2) * FP + tx * 4];
        float4 w3 = *(const float4*)&Ws[(kq * 4 + 3) * FP + tx * 4];
        #pragma unroll
        for (int i = 0; i < 2; ++i) {
            float4 xv = *(const float4*)&xs[(tg * 2 + i) * KP + kq * 4];
            acc[i].x += xv.x * w0.x + xv.y * w1.x + xv.z * w2.x + xv.w * w3.x;
            acc[i].y += xv.x * w0.y + xv.y * w1.y + xv.z * w2.y + xv.w * w3.y;
            acc[i].z += xv.x * w0.z + xv.y * w1.z + xv.z * w2.z + xv.w * w3.z;
            acc[i].w += xv.x * w0.w + xv.y * w1.w + xv.z * w2.w + xv.w * w3.w;
        }
    }

    #pragma unroll
    for (int i = 0; i < 2; ++i) {
        int n = n0 + tg * 2 + i;
        if (n < N && tx * 4 < F) {
            float d = dinv[n];
            ushort4 o;
            o.x = fbf(acc[i].x * d);
            o.y = fbf(acc[i].y * d);
            o.z = fbf(acc[i].z * d);
            o.w = fbf(acc[i].w * d);
            *(ushort4*)(out + (size_t)n * F + tx * 4) = o;
        }
    }
}

// ======================= final gather (40-wide) + bias + log_softmax =======================
// fq clamped to 0..9 so no lane fetches beyond the 80B row.

__launch_bounds__(256)
__global__ void gather40w_lsm(const unsigned short* __restrict__ g, const float* __restrict__ dinv,
                              const int* __restrict__ row_ptr, const int* __restrict__ csr_src,
                              const float* __restrict__ b3, float* __restrict__ out, int N) {
    int gid = blockIdx.x * blockDim.x + threadIdx.x;
    int n = gid >> 6;
    if (n >= N) return;
    int lane = gid & 63;
    const int grp = lane >> 4;          // edge slot 0..3
    const int fq  = lane & 15;
    const int fqc = min(fq, 9);         // lanes fq>=10 duplicate quad 9 (same line)

    int e0 = row_ptr[n], e1 = row_ptr[n + 1];

    float4 acc = make_float4(0.f, 0.f, 0.f, 0.f);
    {
        uint2 u = *(const uint2*)(g + (size_t)n * NCLASS + fqc * 4);
        if (grp == 0) acc = up4(u);
    }

    int e = e0;
    for (; e + 8 <= e1; e += 8) {
        int sA = csr_src[e + grp];
        int sB = csr_src[e + 4 + grp];
        uint2 uA = *(const uint2*)(g + (size_t)sA * NCLASS + fqc * 4);
        uint2 uB = *(const uint2*)(g + (size_t)sB * NCLASS + fqc * 4);
        float4 a = up4(uA), b = up4(uB);
        acc.x += a.x + b.x; acc.y += a.y + b.y;
        acc.z += a.z + b.z; acc.w += a.w + b.w;
    }
    if (e + 4 <= e1) {
        int s = csr_src[e + grp];
        uint2 u = *(const uint2*)(g + (size_t)s * NCLASS + fqc * 4);
        float4 a = up4(u);
        acc.x += a.x; acc.y += a.y; acc.z += a.z; acc.w += a.w;
        e += 4;
    }
    int m = e1 - e;
    if (m > 0) {
        int s = csr_src[(e + grp < e1) ? e + grp : e1 - 1];
        uint2 u = *(const uint2*)(g + (size_t)s * NCLASS + fqc * 4);
        if (grp < m) {
            float4 a = up4(u);
            acc.x += a.x; acc.y += a.y; acc.z += a.z; acc.w += a.w;
        }
    }

    #pragma unroll
    for (int off = 16; off <= 32; off <<= 1) {
        acc.x += __shfl_xor(acc.x, off, 64);
        acc.y += __shfl_xor(acc.y, off, 64);
        acc.z += __shfl_xor(acc.z, off, 64);
        acc.w += __shfl_xor(acc.w, off, 64);
    }

    float d = dinv[n];
    float4 b = *(const float4*)(b3 + fqc * 4);
    float4 v = make_float4(acc.x * d + b.x, acc.y * d + b.y,
                           acc.z * d + b.z, acc.w * d + b.w);
    float lm = (fq < 10) ? fmaxf(fmaxf(v.x, v.y), fmaxf(v.z, v.w)) : -1e30f;
    #pragma unroll
    for (int off = 1; off < 16; off <<= 1)
        lm = fmaxf(lm, __shfl_xor(lm, off, 64));
    float ls = (fq < 10) ? (expf(v.x - lm) + expf(v.y - lm) + expf(v.z - lm) + expf(v.w - lm)) : 0.f;
    #pragma unroll
    for (int off = 1; off < 16; off <<= 1)
        ls += __shfl_xor(ls, off, 64);
    float lg = lm + logf(ls);
    if (grp == 0 && fq < 10) {
        float4 o = make_float4(v.x - lg, v.y - lg, v.z - lg, v.w - lg);
        *(float4*)(out + (size_t)n * NCLASS + fq * 4) = o;
    }
}

// ======================= launch =======================

extern "C" void kernel_launch(void* const* d_in, const int* in_sizes, int n_in,
                              void* d_out, int out_size, void* d_ws, size_t ws_size,
                              hipStream_t stream) {
    const float* x  = (const float*)d_in[0];
    const int*   ei = (const int*)  d_in[1];
    const float* W1 = (const float*)d_in[2];
    const float* b1 = (const float*)d_in[3];
    const float* W2 = (const float*)d_in[4];
    const float* b2 = (const float*)d_in[5];
    const float* W3 = (const float*)d_in[6];
    const float* b3 = (const float*)d_in[7];
    const int N = in_sizes[0] / NFEAT;
    const int E = in_sizes[1] / 2;
    const int* src = ei;
    const int* dst = ei + E;
    float* out = (float*)d_out;

    const int nbin = (N + (1 << BSH) - 1) >> BSH;          // 391

    // ---- workspace layout (4-byte units, 256-aligned sections) ----
    const size_t Np = ((size_t)N + 256) & ~(size_t)255;
    const size_t Ep = ((size_t)E + 255) & ~(size_t)255;
    const size_t Fp = (((size_t)N * 32) + 255) & ~(size_t)255;   // N*64 bf16 in floats
    float* base = (float*)d_ws;
    size_t off = 0;
    int*      gcount  = (int*)(base + off);  off += MAXBIN;
    int*      gbase   = (int*)(base + off);  off += MAXBIN + 256;
    int*      gcur    = (int*)(base + off);  off += MAXBIN;
    int*      row_ptr = (int*)(base + off);  off += Np;
    float*    dinv    =        base + off;   off += Np;
    unsigned* ebuf    = (unsigned*)(base + off); off += Ep;
    int*      csr_src = (int*)(base + off);  off += Ep;
    unsigned short* tb = (unsigned short*)(base + off); off += Fp;  // g1, then g3 (40-wide)
    unsigned short* ab = (unsigned short*)(base + off); off += Fp;  // g2
    // total ~ 39 MB

    const int nchunk = (E + CH - 1) / CH;

    // ---- CSR build (also produces dinv) ----
    hipMemsetAsync(gcount, 0, MAXBIN * sizeof(int), stream);
    binA1<<<nchunk, 256, 0, stream>>>(dst, gcount, E, nbin);
    binscan<<<1, 512, 0, stream>>>(gcount, gbase, gcur, row_ptr, nbin, N, E);
    binA2<<<nchunk, 256, 0, stream>>>(src, dst, gcur, ebuf, E, nbin);
    binB<<<nbin, 256, 0, stream>>>(ebuf, gbase, row_ptr, dinv, csr_src, N);

    // ---- layer 1: g1 = dinv * (x @ W1) ----
    lin1_kernel<<<(N + 63) / 64, 256, 0, stream>>>(x, W1, dinv, tb, N);

    // ---- layer 2 fused: g2 = dinv * ( relu(gather(g1) + b1) @ W2 ) ----
    fused_gather_lin<NHID><<<(N + 31) / 32, 256, 0, stream>>>(
        tb, dinv, row_ptr, csr_src, W2, b1, ab, N);

    // ---- layer 3 fused: g3 = dinv * ( relu(gather(g2) + b2) @ W3 ) ----
    fused_gather_lin<NCLASS><<<(N + 31) / 32, 256, 0, stream>>>(
        ab, dinv, row_ptr, csr_src, W3, b2, tb, N);

    // ---- final gather + bias + log_softmax ----
    const int gatherBlocks = (int)(((size_t)N * 64 + 255) / 256);
    gather40w_lsm<<<gatherBlocks, 256, 0, stream>>>(tb, dinv, row_ptr, csr_src, b3, out, N);
}